// Round 10
// baseline (96.563 us; speedup 1.0000x reference)
//
#include <hip/hip_runtime.h>

// SeparateSourceDense: out[n,:] = x[n,:] @ kernel[source[n]] + bias[source[n],:]
// N=8192, F=256, OUT=256, S=16.
// Round 10: DIAGNOSTIC build. r8 kernel (best, 21.68us) wrapped in a x4
// repeat loop with asm-opaque pointer offsets (prevents load CSE/hoisting),
// so the dispatch exceeds the harness's ~40us ws-poison fills and finally
// surfaces in rocprof top-5 WITH counters. Output written 4x identically ->
// deterministic, absmax unchanged (0.03125 tripwire).

#define NROWS 8192
#define FDIM  256
#define ODIM  256
#define NSRC  16

#define BM 64
#define BN 64
#define LDA 264          // LDS row stride (shorts): 528 B, 16B-aligned
#define MCHUNKS 8
#define NWG (NSRC * MCHUNKS * 4)   // 512
#define TILE_BYTES 16640           // one fp32 [64][65] tile
#define REPEAT 4

typedef float f32x4 __attribute__((ext_vector_type(4)));
typedef short s16x8 __attribute__((ext_vector_type(8)));

__device__ __forceinline__ uint f2bf(float f) {
    union { float f; uint u; } v; v.f = f;              // RNE, inputs finite
    return (v.u + 0x7fffu + ((v.u >> 16) & 1u)) >> 16;
}
__device__ __forceinline__ uint pk2(float lo, float hi) {
    return f2bf(lo) | (f2bf(hi) << 16);
}

__global__ __launch_bounds__(256) void fused_k(
        const float* __restrict__ x,
        const int* __restrict__ source,
        const float* __restrict__ kern,
        const float* __restrict__ bias,
        float* __restrict__ out) {
    // XCD-chunked swizzle: XCD c gets contiguous wg range [c*64, c*64+64)
    const int bid = blockIdx.x;
    const int wg  = (bid & 7) * (NWG / 8) + (bid >> 3);
    const int tile = wg >> 2;
    const int s    = tile / MCHUNKS;
    const int mc   = tile % MCHUNKS;
    const int n0   = (wg & 3) * BN;
    const int lo0  = mc * BM;

    const int t    = threadIdx.x;
    const int lane = t & 63;
    const int wid  = t >> 6;

    __shared__ int   wsum[4];
    __shared__ int   rows_lds[BM];
    __shared__ short b_lds[BN * LDA];                   // 33 KB
    __shared__ __align__(16) char u_buf[BM * LDA * 2];  // 33792 B (tiles+a_lds)
    short* a_lds = (short*)u_buf;

    const int r0 = t >> 4;                      // 0..15
    const int c4 = (t & 15) * 4;                // 0..60
    const int ar = t >> 2;
    const int ac = (t & 3) * 8;
    const int wr = (wid >> 1) * 32;
    const int wc = (wid & 1) * 32;
    const int lr = lane & 15;
    const int lg = lane >> 4;

    int zero;
    asm volatile("v_mov_b32 %0, 0" : "=v"(zero));

    #pragma unroll 1
    for (int rep = 0; rep < REPEAT; ++rep) {
        asm volatile("" : "+v"(zero));          // re-opaque each iteration
        const float* xp  = x + zero;
        const int*   srp = source + zero;
        const float* kp  = kern + zero;
        const float* bp  = bias + zero;
        float*       op  = out + zero;
        if (rep) __syncthreads();               // prev epilogue rows_lds reads

        // ---- issue source loads ----
        int4 sv[8];
        const int4* sp = (const int4*)srp + (size_t)t * 8;
        #pragma unroll
        for (int i = 0; i < 8; ++i) sv[i] = sp[i];

        // ---- issue W loads (independent; drain under scan) ----
        const float* wbase = kp + ((size_t)s * FDIM + r0) * ODIM + n0 + c4;
        float4 wv[4][4];
        #pragma unroll
        for (int j = 0; j < 4; ++j)
            #pragma unroll
            for (int u = 0; u < 4; ++u)
                wv[j][u] = *(const float4*)(wbase + (size_t)(64 * j + 16 * u) * ODIM);

        // ---- scan ----
        int c = 0;
        #pragma unroll
        for (int i = 0; i < 8; ++i)
            c += (sv[i].x == s) + (sv[i].y == s) + (sv[i].z == s) + (sv[i].w == s);
        int p = c;
        #pragma unroll
        for (int d = 1; d < 64; d <<= 1) {
            const int v = __shfl_up(p, d);
            if (lane >= d) p += v;
        }
        if (lane == 63) wsum[wid] = p;
        __syncthreads();
        int r_base = p - c;
        #pragma unroll
        for (int w = 0; w < 4; ++w) if (w < wid) r_base += wsum[w];
        const int cnt = wsum[0] + wsum[1] + wsum[2] + wsum[3];
        if (cnt <= lo0) return;                 // dead block: exits on rep 0

        // ---- first scatter ----
        {
            int r = r_base;
            #pragma unroll
            for (int i = 0; i < 8; ++i) {
                const int base = t * 32 + i * 4;
                if (sv[i].x == s) { if (r >= lo0 && r < lo0 + BM) rows_lds[r - lo0] = base;     ++r; }
                if (sv[i].y == s) { if (r >= lo0 && r < lo0 + BM) rows_lds[r - lo0] = base + 1; ++r; }
                if (sv[i].z == s) { if (r >= lo0 && r < lo0 + BM) rows_lds[r - lo0] = base + 2; ++r; }
                if (sv[i].w == s) { if (r >= lo0 && r < lo0 + BM) rows_lds[r - lo0] = base + 3; ++r; }
            }
        }

        const float bv0 = bp[s * ODIM + n0 + wc + lr];
        const float bv1 = bp[s * ODIM + n0 + wc + 16 + lr];
        const int col0 = n0 + wc + lr;

        int lo = lo0;
        bool first = true;
        while (true) {
            const int nvalid = min(BM, cnt - lo);
            __syncthreads();                    // rows_lds published

            const float* xrow = xp + (size_t)rows_lds[(ar < nvalid) ? ar : 0] * FDIM + ac;
            float4 xv[16];
            #pragma unroll
            for (int j = 0; j < 8; ++j) {
                xv[2 * j]     = *(const float4*)(xrow + j * 32);
                xv[2 * j + 1] = *(const float4*)(xrow + j * 32 + 4);
            }

            if (first) {
                first = false;
                #pragma unroll
                for (int j = 0; j < 4; ++j) {
                    float (*tf)[65] = (float (*)[65])(u_buf + (j & 1) * TILE_BYTES);
                    #pragma unroll
                    for (int u = 0; u < 4; ++u) {
                        tf[r0 + 16 * u][c4 + 0] = wv[j][u].x;
                        tf[r0 + 16 * u][c4 + 1] = wv[j][u].y;
                        tf[r0 + 16 * u][c4 + 2] = wv[j][u].z;
                        tf[r0 + 16 * u][c4 + 3] = wv[j][u].w;
                    }
                    __syncthreads();
                    #pragma unroll
                    for (int u = 0; u < 4; ++u) {
                        const int o_loc = r0 + 16 * u;
                        ushort4 q;
                        q.x = (ushort)f2bf(tf[c4 + 0][o_loc]);
                        q.y = (ushort)f2bf(tf[c4 + 1][o_loc]);
                        q.z = (ushort)f2bf(tf[c4 + 2][o_loc]);
                        q.w = (ushort)f2bf(tf[c4 + 3][o_loc]);
                        *(ushort4*)&b_lds[o_loc * LDA + 64 * j + c4] = q;
                    }
                }
                __syncthreads();                // tile reads done (a_lds aliases)
            }

            {
                short* dst = &a_lds[ar * LDA + ac];
                #pragma unroll
                for (int j = 0; j < 8; ++j) {
                    const float4 f0 = xv[2 * j];
                    const float4 f1 = xv[2 * j + 1];
                    uint4 pk;
                    pk.x = pk2(f0.x, f0.y);
                    pk.y = pk2(f0.z, f0.w);
                    pk.z = pk2(f1.x, f1.y);
                    pk.w = pk2(f1.z, f1.w);
                    *(uint4*)(dst + j * 32) = pk;
                }
            }
            __syncthreads();                    // a_lds + b_lds ready

            f32x4 acc00 = {}, acc01 = {}, acc10 = {}, acc11 = {};
            const short* ab = &a_lds[(wr + lr) * LDA + 8 * lg];
            const short* bb = &b_lds[(wc + lr) * LDA + 8 * lg];
            #pragma unroll 2
            for (int kk = 0; kk < 8; ++kk) {
                const s16x8 a0 = *(const s16x8*)(ab + kk * 32);
                const s16x8 a1 = *(const s16x8*)(ab + kk * 32 + 16 * LDA);
                const s16x8 b0 = *(const s16x8*)(bb + kk * 32);
                const s16x8 b1 = *(const s16x8*)(bb + kk * 32 + 16 * LDA);
                acc00 = __builtin_amdgcn_mfma_f32_16x16x32_bf16(a0, b0, acc00, 0, 0, 0);
                acc01 = __builtin_amdgcn_mfma_f32_16x16x32_bf16(a0, b1, acc01, 0, 0, 0);
                acc10 = __builtin_amdgcn_mfma_f32_16x16x32_bf16(a1, b0, acc10, 0, 0, 0);
                acc11 = __builtin_amdgcn_mfma_f32_16x16x32_bf16(a1, b1, acc11, 0, 0, 0);
            }

            #pragma unroll
            for (int rr = 0; rr < 4; ++rr) {
                int lm = wr + 4 * lg + rr;
                if (lm < nvalid) {
                    float* orow = op + (size_t)rows_lds[lm] * ODIM;
                    orow[col0]      = acc00[rr] + bv0;
                    orow[col0 + 16] = acc01[rr] + bv1;
                }
                lm += 16;
                if (lm < nvalid) {
                    float* orow = op + (size_t)rows_lds[lm] * ODIM;
                    orow[col0]      = acc10[rr] + bv0;
                    orow[col0 + 16] = acc11[rr] + bv1;
                }
            }

            lo += BM;
            if (!(mc == MCHUNKS - 1 && lo < cnt)) break;
            __syncthreads();
            {
                int r = r_base;
                #pragma unroll
                for (int i = 0; i < 8; ++i) {
                    const int4 s2 = sp[i];
                    const int base = t * 32 + i * 4;
                    if (s2.x == s) { if (r >= lo && r < lo + BM) rows_lds[r - lo] = base;     ++r; }
                    if (s2.y == s) { if (r >= lo && r < lo + BM) rows_lds[r - lo] = base + 1; ++r; }
                    if (s2.z == s) { if (r >= lo && r < lo + BM) rows_lds[r - lo] = base + 2; ++r; }
                    if (s2.w == s) { if (r >= lo && r < lo + BM) rows_lds[r - lo] = base + 3; ++r; }
                }
            }
        }
    }
}

// ---------------------------------------------------------------------------
extern "C" void kernel_launch(void* const* d_in, const int* in_sizes, int n_in,
                              void* d_out, int out_size, void* d_ws, size_t ws_size,
                              hipStream_t stream) {
    const float* x      = (const float*)d_in[0];
    const int*   source = (const int*)d_in[1];
    const float* kern   = (const float*)d_in[2];
    const float* bias   = (const float*)d_in[3];
    float*       out    = (float*)d_out;

    hipLaunchKernelGGL(fused_k, dim3(NWG), dim3(256), 0, stream,
                       x, source, kern, bias, out);
}

// Round 11
// 24.102 us; speedup vs baseline: 4.0064x; 4.0064x over previous
//
#include <hip/hip_runtime.h>

// SeparateSourceDense: out[n,:] = x[n,:] @ kernel[source[n]] + bias[source[n],:]
// N=8192, F=256, OUT=256, S=16.
// Round 11: TLP push per r10 counters (69% stall at 2 blocks/CU; 3.7K cyc/CU
// bank conflicts on MFMA b128 reads).
//   - a_lds deleted: A-fragments global->VGPR, issued right after rows_lds
//     barrier, packed under the W-transpose (latency hidden)
//   - LDS 50.7 KB (b_lds 33 + fp32 tile 16.6) + __launch_bounds__(256,3)
//     + grid 768 -> 3 blocks/CU resident
//   - b_lds XOR-swizzled (byte ^= (row&7)<<4) on write and read: kills the
//     LDA=264 stride-4-mod-32 8-way conflict
//   - single pass (MCHUNKS=12 covers cnt<=768; no overflow loop)

#define NROWS 8192
#define FDIM  256
#define ODIM  256
#define NSRC  16

#define BM 64
#define BN 64
#define LDA  264         // shorts per b_lds row
#define LDAB 528         // bytes per b_lds row (16B-aligned)
#define MCHUNKS 12
#define NWG (NSRC * MCHUNKS * 4)   // 768

typedef float f32x4 __attribute__((ext_vector_type(4)));
typedef short s16x8 __attribute__((ext_vector_type(8)));

__device__ __forceinline__ uint f2bf(float f) {
    union { float f; uint u; } v; v.f = f;              // RNE, inputs finite
    return (v.u + 0x7fffu + ((v.u >> 16) & 1u)) >> 16;
}
__device__ __forceinline__ uint pk2(float lo, float hi) {
    return f2bf(lo) | (f2bf(hi) << 16);
}

__global__ __launch_bounds__(256, 3) void fused_k(
        const float* __restrict__ x,
        const int* __restrict__ source,
        const float* __restrict__ kern,
        const float* __restrict__ bias,
        float* __restrict__ out) {
    // XCD-chunked swizzle: XCD c gets contiguous wg range [c*96, c*96+96)
    const int bid = blockIdx.x;
    const int wg  = (bid & 7) * (NWG / 8) + (bid >> 3);
    const int tile = wg >> 2;
    const int s    = tile / MCHUNKS;
    const int mc   = tile % MCHUNKS;
    const int n0   = (wg & 3) * BN;
    const int lo   = mc * BM;

    const int t    = threadIdx.x;
    const int lane = t & 63;
    const int wid  = t >> 6;

    __shared__ int   wsum[4];
    __shared__ int   rows_lds[BM];
    __shared__ short b_lds[BN * LDA];                   // 33 KB
    __shared__ float tile_f[64][65];                    // 16.6 KB

    // ---- issue source loads (scan consumes first) ----
    int4 sv[8];
    const int4* sp = (const int4*)source + (size_t)t * 8;
    #pragma unroll
    for (int i = 0; i < 8; ++i) sv[i] = sp[i];

    // ---- issue W loads (independent; drain under scan/scatter) ----
    const int r0 = t >> 4;                      // 0..15
    const int c4 = (t & 15) * 4;                // 0..60
    const float* wbase = kern + ((size_t)s * FDIM + r0) * ODIM + n0 + c4;
    float4 wv[4][4];
    #pragma unroll
    for (int j = 0; j < 4; ++j)
        #pragma unroll
        for (int u = 0; u < 4; ++u)
            wv[j][u] = *(const float4*)(wbase + (size_t)(64 * j + 16 * u) * ODIM);

    // ---- scan: thread t owns rows [32t, 32t+32) ----
    int c = 0;
    #pragma unroll
    for (int i = 0; i < 8; ++i)
        c += (sv[i].x == s) + (sv[i].y == s) + (sv[i].z == s) + (sv[i].w == s);
    int p = c;
    #pragma unroll
    for (int d = 1; d < 64; d <<= 1) {
        const int v = __shfl_up(p, d);
        if (lane >= d) p += v;
    }
    if (lane == 63) wsum[wid] = p;
    __syncthreads();
    int r = p - c;                              // exclusive prefix in wave
    #pragma unroll
    for (int w = 0; w < 4; ++w) if (w < wid) r += wsum[w];
    const int cnt = wsum[0] + wsum[1] + wsum[2] + wsum[3];
    if (cnt <= lo) return;                      // uniform: dead block exits
    const int nvalid = min(BM, cnt - lo);

    // ---- scatter matches landing in [lo, lo+64) ----
    #pragma unroll
    for (int i = 0; i < 8; ++i) {
        const int base = t * 32 + i * 4;
        if (sv[i].x == s) { if (r >= lo && r < lo + BM) rows_lds[r - lo] = base;     ++r; }
        if (sv[i].y == s) { if (r >= lo && r < lo + BM) rows_lds[r - lo] = base + 1; ++r; }
        if (sv[i].z == s) { if (r >= lo && r < lo + BM) rows_lds[r - lo] = base + 2; ++r; }
        if (sv[i].w == s) { if (r >= lo && r < lo + BM) rows_lds[r - lo] = base + 3; ++r; }
    }
    __syncthreads();                            // rows_lds published

    // ---- fragment coordinates ----
    const int wr = (wid >> 1) * 32;
    const int wc = (wid & 1) * 32;
    const int lr = lane & 15;
    const int lg = lane >> 4;
    const int swx = (lr & 7) << 4;              // read-side byte XOR

    // ---- A batch 0: issue loads NOW (pack after transpose halves) ----
    const int row0 = rows_lds[(wr + lr      < nvalid) ? (wr + lr)      : 0];
    const int row1 = rows_lds[(wr + lr + 16 < nvalid) ? (wr + lr + 16) : 0];
    const float* xa0 = x + (size_t)row0 * FDIM + 8 * lg;
    const float* xa1 = x + (size_t)row1 * FDIM + 8 * lg;

    float4 a0[8], a0b[8];
    #pragma unroll
    for (int kk = 0; kk < 8; ++kk) {
        a0[kk]  = *(const float4*)(xa0 + 32 * kk);
        a0b[kk] = *(const float4*)(xa0 + 32 * kk + 4);
    }

    // ---- transpose subtiles 0,1 (consumes wv[0..1]) ----
    #pragma unroll
    for (int j = 0; j < 2; ++j) {
        if (j) __syncthreads();                 // reads of subtile j-1 done
        #pragma unroll
        for (int u = 0; u < 4; ++u) {
            tile_f[r0 + 16 * u][c4 + 0] = wv[j][u].x;
            tile_f[r0 + 16 * u][c4 + 1] = wv[j][u].y;
            tile_f[r0 + 16 * u][c4 + 2] = wv[j][u].z;
            tile_f[r0 + 16 * u][c4 + 3] = wv[j][u].w;
        }
        __syncthreads();
        #pragma unroll
        for (int u = 0; u < 4; ++u) {
            const int o_loc = r0 + 16 * u;
            ushort4 q;
            q.x = (ushort)f2bf(tile_f[c4 + 0][o_loc]);
            q.y = (ushort)f2bf(tile_f[c4 + 1][o_loc]);
            q.z = (ushort)f2bf(tile_f[c4 + 2][o_loc]);
            q.w = (ushort)f2bf(tile_f[c4 + 3][o_loc]);
            const int boff = (128 * j + 2 * c4) ^ ((o_loc & 7) << 4);
            *(ushort4*)((char*)b_lds + (size_t)o_loc * LDAB + boff) = q;
        }
    }

    // ---- pack A batch 0 (loads drained under transpose) ----
    s16x8 pa0[8];
    #pragma unroll
    for (int kk = 0; kk < 8; ++kk) {
        uint4 ua;
        ua.x = pk2(a0[kk].x, a0[kk].y);
        ua.y = pk2(a0[kk].z, a0[kk].w);
        ua.z = pk2(a0b[kk].x, a0b[kk].y);
        ua.w = pk2(a0b[kk].z, a0b[kk].w);
        pa0[kk] = *(const s16x8*)&ua;
    }

    // ---- A batch 1: issue (drains under transpose 2,3) ----
    float4 a1[8], a1b[8];
    #pragma unroll
    for (int kk = 0; kk < 8; ++kk) {
        a1[kk]  = *(const float4*)(xa1 + 32 * kk);
        a1b[kk] = *(const float4*)(xa1 + 32 * kk + 4);
    }

    // ---- transpose subtiles 2,3 (consumes wv[2..3]) ----
    #pragma unroll
    for (int j = 2; j < 4; ++j) {
        __syncthreads();                        // reads of subtile j-1 done
        #pragma unroll
        for (int u = 0; u < 4; ++u) {
            tile_f[r0 + 16 * u][c4 + 0] = wv[j][u].x;
            tile_f[r0 + 16 * u][c4 + 1] = wv[j][u].y;
            tile_f[r0 + 16 * u][c4 + 2] = wv[j][u].z;
            tile_f[r0 + 16 * u][c4 + 3] = wv[j][u].w;
        }
        __syncthreads();
        #pragma unroll
        for (int u = 0; u < 4; ++u) {
            const int o_loc = r0 + 16 * u;
            ushort4 q;
            q.x = (ushort)f2bf(tile_f[c4 + 0][o_loc]);
            q.y = (ushort)f2bf(tile_f[c4 + 1][o_loc]);
            q.z = (ushort)f2bf(tile_f[c4 + 2][o_loc]);
            q.w = (ushort)f2bf(tile_f[c4 + 3][o_loc]);
            const int boff = (128 * j + 2 * c4) ^ ((o_loc & 7) << 4);
            *(ushort4*)((char*)b_lds + (size_t)o_loc * LDAB + boff) = q;
        }
    }

    // ---- pack A batch 1 ----
    s16x8 pa1[8];
    #pragma unroll
    for (int kk = 0; kk < 8; ++kk) {
        uint4 ua;
        ua.x = pk2(a1[kk].x, a1[kk].y);
        ua.y = pk2(a1[kk].z, a1[kk].w);
        ua.z = pk2(a1b[kk].x, a1b[kk].y);
        ua.w = pk2(a1b[kk].z, a1b[kk].w);
        pa1[kk] = *(const s16x8*)&ua;
    }

    __syncthreads();                            // all b_lds writes visible

    // ---- MFMA: A from regs, B from swizzled LDS ----
    f32x4 acc00 = {}, acc01 = {}, acc10 = {}, acc11 = {};
    const char* bp0 = (const char*)b_lds + (size_t)(wc + lr) * LDAB;
    const char* bp1 = bp0 + (size_t)16 * LDAB;
    #pragma unroll
    for (int kk = 0; kk < 8; ++kk) {
        const int off = (16 * lg + 64 * kk) ^ swx;
        const s16x8 b0 = *(const s16x8*)(bp0 + off);
        const s16x8 b1 = *(const s16x8*)(bp1 + off);
        acc00 = __builtin_amdgcn_mfma_f32_16x16x32_bf16(pa0[kk], b0, acc00, 0, 0, 0);
        acc01 = __builtin_amdgcn_mfma_f32_16x16x32_bf16(pa0[kk], b1, acc01, 0, 0, 0);
        acc10 = __builtin_amdgcn_mfma_f32_16x16x32_bf16(pa1[kk], b0, acc10, 0, 0, 0);
        acc11 = __builtin_amdgcn_mfma_f32_16x16x32_bf16(pa1[kk], b1, acc11, 0, 0, 0);
    }

    // ---- epilogue: D[row=4*lg+rr][col=lr]; bias add + row scatter ----
    const float bv0 = bias[s * ODIM + n0 + wc + lr];
    const float bv1 = bias[s * ODIM + n0 + wc + 16 + lr];
    const int col0 = n0 + wc + lr;
    #pragma unroll
    for (int rr = 0; rr < 4; ++rr) {
        int lm = wr + 4 * lg + rr;
        if (lm < nvalid) {
            float* orow = out + (size_t)rows_lds[lm] * ODIM;
            orow[col0]      = acc00[rr] + bv0;
            orow[col0 + 16] = acc01[rr] + bv1;
        }
        lm += 16;
        if (lm < nvalid) {
            float* orow = out + (size_t)rows_lds[lm] * ODIM;
            orow[col0]      = acc10[rr] + bv0;
            orow[col0 + 16] = acc11[rr] + bv1;
        }
    }
}

// ---------------------------------------------------------------------------
extern "C" void kernel_launch(void* const* d_in, const int* in_sizes, int n_in,
                              void* d_out, int out_size, void* d_ws, size_t ws_size,
                              hipStream_t stream) {
    const float* x      = (const float*)d_in[0];
    const int*   source = (const int*)d_in[1];
    const float* kern   = (const float*)d_in[2];
    const float* bias   = (const float*)d_in[3];
    float*       out    = (float*)d_out;

    hipLaunchKernelGGL(fused_k, dim3(NWG), dim3(256), 0, stream,
                       x, source, kern, bias, out);
}

// Round 12
// 22.506 us; speedup vs baseline: 4.2905x; 1.0709x over previous
//
#include <hip/hip_runtime.h>

// SeparateSourceDense: out[n,:] = x[n,:] @ kernel[source[n]] + bias[source[n],:]
// N=8192, F=256, OUT=256, S=16.
// Round 12: r8 algorithm restructured to 512-thread / 8-wave blocks.
// Same LDS (66KB -> 2 blocks/CU) but 16 waves/CU (was 8): doubles TLP against
// the measured 69% dependency-stall; halves per-thread serial work in every
// phase. Wave grid 2x4, each wave 32x16 output (2 MFMAs/kk). No swizzle
// (bank patterns are already uniform-8 for b128 = the floor). r8's overflow
// loop + load-early discipline retained. Numerics bit-identical to r3-r11.

#define NROWS 8192
#define FDIM  256
#define ODIM  256
#define NSRC  16

#define BM 64
#define BN 64
#define LDA  264         // shorts per LDS row
#define LDAB 528         // bytes per LDS row (16B-aligned)
#define MCHUNKS 8
#define NWG (NSRC * MCHUNKS * 4)   // 512 blocks = exactly co-resident at 2/CU
#define TILE_BYTES 16640           // one fp32 [64][65] tile

typedef float f32x4 __attribute__((ext_vector_type(4)));
typedef short s16x8 __attribute__((ext_vector_type(8)));

__device__ __forceinline__ uint f2bf(float f) {
    union { float f; uint u; } v; v.f = f;              // RNE, inputs finite
    return (v.u + 0x7fffu + ((v.u >> 16) & 1u)) >> 16;
}
__device__ __forceinline__ uint pk2(float lo, float hi) {
    return f2bf(lo) | (f2bf(hi) << 16);
}

__global__ __launch_bounds__(512, 4) void fused_k(
        const float* __restrict__ x,
        const int* __restrict__ source,
        const float* __restrict__ kern,
        const float* __restrict__ bias,
        float* __restrict__ out) {
    // XCD-chunked swizzle: XCD c gets contiguous wg range [c*64, c*64+64)
    const int bid = blockIdx.x;
    const int wg  = (bid & 7) * (NWG / 8) + (bid >> 3);
    const int tile = wg >> 2;
    const int s    = tile / MCHUNKS;
    const int mc   = tile % MCHUNKS;
    const int n0   = (wg & 3) * BN;
    const int lo0  = mc * BM;

    const int t    = threadIdx.x;
    const int lane = t & 63;
    const int wid  = t >> 6;                    // 0..7

    __shared__ int   wsum[8];
    __shared__ int   rows_lds[BM];
    __shared__ short b_lds[BN * LDA];                   // 33 KB
    __shared__ __align__(16) char u_buf[BM * LDA * 2];  // 33792 B: 2 tiles / a_lds
    short* a_lds = (short*)u_buf;

    const int r0 = t >> 4;                      // 0..31 (W-load k-row)
    const int c4 = (t & 15) * 4;                // 0..60 (W-load o-col)
    const int c8 = (t & 7) * 8;                 // 0..56 (transpose-read k-col)
    const int ol = t >> 3;                      // 0..63 (transpose-write o-row)
    const int ar = t >> 3;                      // 0..63 (A-stage row)
    const int ac = (t & 7) * 32;                // A-stage col (floats)
    const int wr = (wid >> 2) * 32;             // wave row offset {0,32}
    const int wc = (wid & 3) * 16;              // wave col offset {0,16,32,48}
    const int lr = lane & 15;
    const int lg = lane >> 4;

    // ---- issue source loads (scan consumes first) ----
    int4 sv[4];
    const int4* sp = (const int4*)source + (size_t)t * 4;
    #pragma unroll
    for (int i = 0; i < 4; ++i) sv[i] = sp[i];

    // ---- issue W loads (independent; drain under scan/scatter) ----
    const float* wbase = kern + ((size_t)s * FDIM + r0) * ODIM + n0 + c4;
    float4 wv[4][2];
    #pragma unroll
    for (int j = 0; j < 4; ++j)
        #pragma unroll
        for (int u = 0; u < 2; ++u)
            wv[j][u] = *(const float4*)(wbase + (size_t)(64 * j + 32 * u) * ODIM);

    // ---- scan: thread t owns rows [16t, 16t+16) ----
    int c = 0;
    #pragma unroll
    for (int i = 0; i < 4; ++i)
        c += (sv[i].x == s) + (sv[i].y == s) + (sv[i].z == s) + (sv[i].w == s);
    int p = c;
    #pragma unroll
    for (int d = 1; d < 64; d <<= 1) {
        const int v = __shfl_up(p, d);
        if (lane >= d) p += v;
    }
    if (lane == 63) wsum[wid] = p;
    __syncthreads();
    int r_base = p - c;                         // exclusive prefix in wave
    int cnt = 0;
    #pragma unroll
    for (int w = 0; w < 8; ++w) {
        if (w < wid) r_base += wsum[w];
        cnt += wsum[w];
    }
    if (cnt <= lo0) return;                     // uniform: rare idle block

    // ---- first scatter (sv dies here) ----
    {
        int r = r_base;
        #pragma unroll
        for (int i = 0; i < 4; ++i) {
            const int base = t * 16 + i * 4;
            if (sv[i].x == s) { if (r >= lo0 && r < lo0 + BM) rows_lds[r - lo0] = base;     ++r; }
            if (sv[i].y == s) { if (r >= lo0 && r < lo0 + BM) rows_lds[r - lo0] = base + 1; ++r; }
            if (sv[i].z == s) { if (r >= lo0 && r < lo0 + BM) rows_lds[r - lo0] = base + 2; ++r; }
            if (sv[i].w == s) { if (r >= lo0 && r < lo0 + BM) rows_lds[r - lo0] = base + 3; ++r; }
        }
    }

    const float bv0 = bias[s * ODIM + n0 + wc + lr];
    const int col0 = n0 + wc + lr;

    int lo = lo0;
    bool first = true;
    while (true) {
        const int nvalid = min(BM, cnt - lo);
        __syncthreads();                        // rows_lds published

        // issue gathered x loads (8 float4 = one 64-row tile across 512 thr)
        const float* xrow = x + (size_t)rows_lds[(ar < nvalid) ? ar : 0] * FDIM + ac;
        float4 xv[8];
        #pragma unroll
        for (int j = 0; j < 8; ++j)
            xv[j] = *(const float4*)(xrow + 4 * j);

        if (first) {
            first = false;
            // transpose W-slice via double-buffered fp32 tiles -> b_lds[o][k]
            #pragma unroll
            for (int j = 0; j < 4; ++j) {
                float (*tf)[65] = (float (*)[65])(u_buf + (j & 1) * TILE_BYTES);
                #pragma unroll
                for (int u = 0; u < 2; ++u) {
                    tf[r0 + 32 * u][c4 + 0] = wv[j][u].x;
                    tf[r0 + 32 * u][c4 + 1] = wv[j][u].y;
                    tf[r0 + 32 * u][c4 + 2] = wv[j][u].z;
                    tf[r0 + 32 * u][c4 + 3] = wv[j][u].w;
                }
                __syncthreads();                // write(j) done before read(j)
                uint4 q;
                q.x = pk2(tf[c8 + 0][ol], tf[c8 + 1][ol]);
                q.y = pk2(tf[c8 + 2][ol], tf[c8 + 3][ol]);
                q.z = pk2(tf[c8 + 4][ol], tf[c8 + 5][ol]);
                q.w = pk2(tf[c8 + 6][ol], tf[c8 + 7][ol]);
                *(uint4*)((char*)b_lds + (size_t)ol * LDAB + 128 * j + 2 * c8) = q;
                // write(j+1) targets the other tile; write(j+2) reuses this
                // tile only after the sync inside iteration j+1.
            }
            __syncthreads();                    // tile reads done (a_lds aliases)
        }

        // stage gathered A rows (bf16) into a_lds
        {
            char* dst = (char*)a_lds + (size_t)ar * LDAB + 2 * ac;
            #pragma unroll
            for (int i = 0; i < 4; ++i) {
                uint4 pk;
                pk.x = pk2(xv[2 * i].x,     xv[2 * i].y);
                pk.y = pk2(xv[2 * i].z,     xv[2 * i].w);
                pk.z = pk2(xv[2 * i + 1].x, xv[2 * i + 1].y);
                pk.w = pk2(xv[2 * i + 1].z, xv[2 * i + 1].w);
                *(uint4*)(dst + 16 * i) = pk;
            }
        }
        __syncthreads();                        // a_lds + b_lds ready

        // MFMA: 8 waves in 2x4, each 32x16 out (2 frags)
        f32x4 acc0 = {}, acc1 = {};
        const char* ap0 = (const char*)a_lds + (size_t)(wr + lr) * LDAB;
        const char* ap1 = ap0 + (size_t)16 * LDAB;
        const char* bp  = (const char*)b_lds + (size_t)(wc + lr) * LDAB;
        #pragma unroll
        for (int kk = 0; kk < 8; ++kk) {
            const int off = 16 * lg + 64 * kk;
            const s16x8 a0 = *(const s16x8*)(ap0 + off);
            const s16x8 a1 = *(const s16x8*)(ap1 + off);
            const s16x8 b0 = *(const s16x8*)(bp + off);
            acc0 = __builtin_amdgcn_mfma_f32_16x16x32_bf16(a0, b0, acc0, 0, 0, 0);
            acc1 = __builtin_amdgcn_mfma_f32_16x16x32_bf16(a1, b0, acc1, 0, 0, 0);
        }

        // epilogue: D[row=4*lg+rr][col=lr]; bias add + row scatter
        #pragma unroll
        for (int rr = 0; rr < 4; ++rr) {
            int lm = wr + 4 * lg + rr;
            if (lm < nvalid)
                out[(size_t)rows_lds[lm] * ODIM + col0] = acc0[rr] + bv0;
            lm += 16;
            if (lm < nvalid)
                out[(size_t)rows_lds[lm] * ODIM + col0] = acc1[rr] + bv0;
        }

        // overflow: only the last chunk loops (cnt > 512 is a rare tail event)
        lo += BM;
        if (!(mc == MCHUNKS - 1 && lo < cnt)) break;
        __syncthreads();                        // epilogue rows_lds reads done
        {
            int r = r_base;
            #pragma unroll
            for (int i = 0; i < 4; ++i) {
                const int4 s2 = sp[i];          // reload (rare path)
                const int base = t * 16 + i * 4;
                if (s2.x == s) { if (r >= lo && r < lo + BM) rows_lds[r - lo] = base;     ++r; }
                if (s2.y == s) { if (r >= lo && r < lo + BM) rows_lds[r - lo] = base + 1; ++r; }
                if (s2.z == s) { if (r >= lo && r < lo + BM) rows_lds[r - lo] = base + 2; ++r; }
                if (s2.w == s) { if (r >= lo && r < lo + BM) rows_lds[r - lo] = base + 3; ++r; }
            }
        }
    }
}

// ---------------------------------------------------------------------------
extern "C" void kernel_launch(void* const* d_in, const int* in_sizes, int n_in,
                              void* d_out, int out_size, void* d_ws, size_t ws_size,
                              hipStream_t stream) {
    const float* x      = (const float*)d_in[0];
    const int*   source = (const int*)d_in[1];
    const float* kern   = (const float*)d_in[2];
    const float* bias   = (const float*)d_in[3];
    float*       out    = (float*)d_out;

    hipLaunchKernelGGL(fused_k, dim3(NWG), dim3(512), 0, stream,
                       x, source, kern, bias, out);
}

// Round 13
// 20.031 us; speedup vs baseline: 4.8206x; 1.1235x over previous
//
#include <hip/hip_runtime.h>

// SeparateSourceDense: out[n,:] = x[n,:] @ kernel[source[n]] + bias[source[n],:]
// N=8192, F=256, OUT=256, S=16.
// Round 13: r8 with the fp32-LDS-tile W transpose replaced by a REGISTER
// transpose: each thread owns a 4o x 16k patch (float4 loads along o,
// coalesced), pk2-packs along k, writes b_lds[o][k] as 2 b128 per o-row.
// Removes ~128 scalar LDS ops/thread, 16.6KB LDS, and 6 barriers — the
// common bottleneck of r8-r12 (r10 counters: LDS pipe + barrier convoy).

#define NROWS 8192
#define FDIM  256
#define ODIM  256
#define NSRC  16

#define BM 64
#define BN 64
#define LDA  264         // shorts per LDS row
#define LDAB 528         // bytes per LDS row (16B-aligned)
#define MCHUNKS 8
#define NWG (NSRC * MCHUNKS * 4)   // 512 blocks = exactly co-resident at 2/CU

typedef float f32x4 __attribute__((ext_vector_type(4)));
typedef short s16x8 __attribute__((ext_vector_type(8)));

__device__ __forceinline__ uint f2bf(float f) {
    union { float f; uint u; } v; v.f = f;              // RNE, inputs finite
    return (v.u + 0x7fffu + ((v.u >> 16) & 1u)) >> 16;
}
__device__ __forceinline__ uint pk2(float lo, float hi) {
    return f2bf(lo) | (f2bf(hi) << 16);
}
__device__ __forceinline__ float f4get(const float4& v, int k) {
    return k == 0 ? v.x : k == 1 ? v.y : k == 2 ? v.z : v.w;
}

__global__ __launch_bounds__(256) void fused_k(
        const float* __restrict__ x,
        const int* __restrict__ source,
        const float* __restrict__ kern,
        const float* __restrict__ bias,
        float* __restrict__ out) {
    // XCD-chunked swizzle: XCD c gets contiguous wg range [c*64, c*64+64)
    const int bid = blockIdx.x;
    const int wg  = (bid & 7) * (NWG / 8) + (bid >> 3);
    const int tile = wg >> 2;
    const int s    = tile / MCHUNKS;
    const int mc   = tile % MCHUNKS;
    const int n0   = (wg & 3) * BN;
    const int lo0  = mc * BM;

    const int t    = threadIdx.x;
    const int lane = t & 63;
    const int wid  = t >> 6;

    __shared__ int   wsum[4];
    __shared__ int   rows_lds[BM];
    __shared__ short a_lds[BM * LDA];           // 33 KB
    __shared__ short b_lds[BN * LDA];           // 33 KB

    // ---- issue source loads (scan consumes first) ----
    int4 sv[8];
    const int4* sp = (const int4*)source + (size_t)t * 8;
    #pragma unroll
    for (int i = 0; i < 8; ++i) sv[i] = sp[i];

    // ---- issue W patch loads: 4 o (o0..o0+3) x 16 k (k0..k0+15) ----
    // consecutive lanes -> contiguous o: 256B coalesced segments per k-row
    const int k0 = (t >> 4) * 16;               // 0..240
    const int o0 = (t & 15) * 4;                // 0..60
    const float* wbase = kern + ((size_t)s * FDIM + k0) * ODIM + n0 + o0;
    float4 wv[16];
    #pragma unroll
    for (int i = 0; i < 16; ++i)
        wv[i] = *(const float4*)(wbase + (size_t)i * ODIM);

    // ---- scan: thread t owns rows [32t, 32t+32) ----
    int c = 0;
    #pragma unroll
    for (int i = 0; i < 8; ++i)
        c += (sv[i].x == s) + (sv[i].y == s) + (sv[i].z == s) + (sv[i].w == s);
    int p = c;
    #pragma unroll
    for (int d = 1; d < 64; d <<= 1) {
        const int v = __shfl_up(p, d);
        if (lane >= d) p += v;
    }
    if (lane == 63) wsum[wid] = p;
    __syncthreads();
    int r_base = p - c;                         // exclusive prefix in wave
    #pragma unroll
    for (int w = 0; w < 4; ++w) if (w < wid) r_base += wsum[w];
    const int cnt = wsum[0] + wsum[1] + wsum[2] + wsum[3];
    if (cnt <= lo0) return;                     // uniform: rare idle block

    // ---- first scatter (sv dies here) ----
    {
        int r = r_base;
        #pragma unroll
        for (int i = 0; i < 8; ++i) {
            const int base = t * 32 + i * 4;
            if (sv[i].x == s) { if (r >= lo0 && r < lo0 + BM) rows_lds[r - lo0] = base;     ++r; }
            if (sv[i].y == s) { if (r >= lo0 && r < lo0 + BM) rows_lds[r - lo0] = base + 1; ++r; }
            if (sv[i].z == s) { if (r >= lo0 && r < lo0 + BM) rows_lds[r - lo0] = base + 2; ++r; }
            if (sv[i].w == s) { if (r >= lo0 && r < lo0 + BM) rows_lds[r - lo0] = base + 3; ++r; }
        }
    }

    // ---- register-transpose W patch -> b_lds[o][k] (2 b128 per o-row) ----
    #pragma unroll
    for (int j = 0; j < 4; ++j) {
        uint4 q0, q1;
        q0.x = pk2(f4get(wv[0],  j), f4get(wv[1],  j));
        q0.y = pk2(f4get(wv[2],  j), f4get(wv[3],  j));
        q0.z = pk2(f4get(wv[4],  j), f4get(wv[5],  j));
        q0.w = pk2(f4get(wv[6],  j), f4get(wv[7],  j));
        q1.x = pk2(f4get(wv[8],  j), f4get(wv[9],  j));
        q1.y = pk2(f4get(wv[10], j), f4get(wv[11], j));
        q1.z = pk2(f4get(wv[12], j), f4get(wv[13], j));
        q1.w = pk2(f4get(wv[14], j), f4get(wv[15], j));
        char* dst = (char*)b_lds + (size_t)(o0 + j) * LDAB + 2 * k0;
        *(uint4*)(dst)      = q0;
        *(uint4*)(dst + 16) = q1;
    }

    const int ar = t >> 2;
    const int ac = (t & 3) * 8;
    const int wr = (wid >> 1) * 32;
    const int wc = (wid & 1) * 32;
    const int lr = lane & 15;
    const int lg = lane >> 4;

    const float bv0 = bias[s * ODIM + n0 + wc + lr];
    const float bv1 = bias[s * ODIM + n0 + wc + 16 + lr];
    const int col0 = n0 + wc + lr;

    int lo = lo0;
    while (true) {
        const int nvalid = min(BM, cnt - lo);
        __syncthreads();                        // rows_lds + b_lds published

        // issue gathered x loads
        const float* xrow = x + (size_t)rows_lds[(ar < nvalid) ? ar : 0] * FDIM + ac;
        float4 xv[16];
        #pragma unroll
        for (int j = 0; j < 8; ++j) {
            xv[2 * j]     = *(const float4*)(xrow + j * 32);
            xv[2 * j + 1] = *(const float4*)(xrow + j * 32 + 4);
        }

        // stage gathered A rows (bf16) into a_lds
        {
            short* dst = &a_lds[ar * LDA + ac];
            #pragma unroll
            for (int j = 0; j < 8; ++j) {
                const float4 f0 = xv[2 * j];
                const float4 f1 = xv[2 * j + 1];
                uint4 pk;
                pk.x = pk2(f0.x, f0.y);
                pk.y = pk2(f0.z, f0.w);
                pk.z = pk2(f1.x, f1.y);
                pk.w = pk2(f1.z, f1.w);
                *(uint4*)(dst + j * 32) = pk;
            }
        }
        __syncthreads();                        // a_lds + b_lds ready

        // MFMA: 4 waves in 2x2, each 32x32 out
        f32x4 acc00 = {}, acc01 = {}, acc10 = {}, acc11 = {};
        const short* ab = &a_lds[(wr + lr) * LDA + 8 * lg];
        const short* bb = &b_lds[(wc + lr) * LDA + 8 * lg];
        #pragma unroll 2
        for (int kk = 0; kk < 8; ++kk) {
            const s16x8 a0 = *(const s16x8*)(ab + kk * 32);
            const s16x8 a1 = *(const s16x8*)(ab + kk * 32 + 16 * LDA);
            const s16x8 b0 = *(const s16x8*)(bb + kk * 32);
            const s16x8 b1 = *(const s16x8*)(bb + kk * 32 + 16 * LDA);
            acc00 = __builtin_amdgcn_mfma_f32_16x16x32_bf16(a0, b0, acc00, 0, 0, 0);
            acc01 = __builtin_amdgcn_mfma_f32_16x16x32_bf16(a0, b1, acc01, 0, 0, 0);
            acc10 = __builtin_amdgcn_mfma_f32_16x16x32_bf16(a1, b0, acc10, 0, 0, 0);
            acc11 = __builtin_amdgcn_mfma_f32_16x16x32_bf16(a1, b1, acc11, 0, 0, 0);
        }

        // epilogue: D[row=4*lg+rr][col=lr]; bias add + row scatter
        #pragma unroll
        for (int rr = 0; rr < 4; ++rr) {
            int lm = wr + 4 * lg + rr;
            if (lm < nvalid) {
                float* orow = out + (size_t)rows_lds[lm] * ODIM;
                orow[col0]      = acc00[rr] + bv0;
                orow[col0 + 16] = acc01[rr] + bv1;
            }
            lm += 16;
            if (lm < nvalid) {
                float* orow = out + (size_t)rows_lds[lm] * ODIM;
                orow[col0]      = acc10[rr] + bv0;
                orow[col0 + 16] = acc11[rr] + bv1;
            }
        }

        // overflow: only the last chunk loops (cnt > 512 is a rare tail event)
        lo += BM;
        if (!(mc == MCHUNKS - 1 && lo < cnt)) break;
        __syncthreads();                        // epilogue rows_lds reads done
        {
            int r = r_base;
            #pragma unroll
            for (int i = 0; i < 8; ++i) {
                const int4 s2 = sp[i];          // reload (rare path)
                const int base = t * 32 + i * 4;
                if (s2.x == s) { if (r >= lo && r < lo + BM) rows_lds[r - lo] = base;     ++r; }
                if (s2.y == s) { if (r >= lo && r < lo + BM) rows_lds[r - lo] = base + 1; ++r; }
                if (s2.z == s) { if (r >= lo && r < lo + BM) rows_lds[r - lo] = base + 2; ++r; }
                if (s2.w == s) { if (r >= lo && r < lo + BM) rows_lds[r - lo] = base + 3; ++r; }
            }
        }
    }
}

// ---------------------------------------------------------------------------
extern "C" void kernel_launch(void* const* d_in, const int* in_sizes, int n_in,
                              void* d_out, int out_size, void* d_ws, size_t ws_size,
                              hipStream_t stream) {
    const float* x      = (const float*)d_in[0];
    const int*   source = (const int*)d_in[1];
    const float* kern   = (const float*)d_in[2];
    const float* bias   = (const float*)d_in[3];
    float*       out    = (float*)d_out;

    hipLaunchKernelGGL(fused_k, dim3(NWG), dim3(256), 0, stream,
                       x, source, kern, bias, out);
}

// Round 14
// 19.660 us; speedup vs baseline: 4.9116x; 1.0189x over previous
//
#include <hip/hip_runtime.h>

// SeparateSourceDense: out[n,:] = x[n,:] @ kernel[source[n]] + bias[source[n],:]
// N=8192, F=256, OUT=256, S=16.
// Round 14: wave-local A-staging. One __syncthreads total in the main path
// (rows_lds + b_lds publish). Each of the 4 waves owns a 16-row strip:
// gathers its own x rows, stages into its own a_lds region, then a
// WAVE-LOCAL fence (s_waitcnt lgkmcnt(0), same-wave in-order DS pipe) and
// straight into MFMA — no second block barrier, waves slip to hide each
// other's memory latency. W register-transpose (r13) unchanged.

#define NROWS 8192
#define FDIM  256
#define ODIM  256
#define NSRC  16

#define BM 64
#define BN 64
#define LDA  264         // shorts per LDS row
#define LDAB 528         // bytes per LDS row (16B-aligned)
#define MCHUNKS 8
#define NWG (NSRC * MCHUNKS * 4)   // 512 blocks = exactly co-resident at 2/CU

typedef float f32x4 __attribute__((ext_vector_type(4)));
typedef short s16x8 __attribute__((ext_vector_type(8)));

__device__ __forceinline__ uint f2bf(float f) {
    union { float f; uint u; } v; v.f = f;              // RNE, inputs finite
    return (v.u + 0x7fffu + ((v.u >> 16) & 1u)) >> 16;
}
__device__ __forceinline__ uint pk2(float lo, float hi) {
    return f2bf(lo) | (f2bf(hi) << 16);
}
__device__ __forceinline__ float f4get(const float4& v, int k) {
    return k == 0 ? v.x : k == 1 ? v.y : k == 2 ? v.z : v.w;
}

__global__ __launch_bounds__(256) void fused_k(
        const float* __restrict__ x,
        const int* __restrict__ source,
        const float* __restrict__ kern,
        const float* __restrict__ bias,
        float* __restrict__ out) {
    // XCD-chunked swizzle: XCD c gets contiguous wg range [c*64, c*64+64)
    const int bid = blockIdx.x;
    const int wg  = (bid & 7) * (NWG / 8) + (bid >> 3);
    const int tile = wg >> 2;
    const int s    = tile / MCHUNKS;
    const int mc   = tile % MCHUNKS;
    const int n0   = (wg & 3) * BN;
    const int lo0  = mc * BM;

    const int t    = threadIdx.x;
    const int lane = t & 63;
    const int wid  = t >> 6;                    // 0..3: strip rows [16w,16w+16)

    __shared__ int   wsum[4];
    __shared__ int   rows_lds[BM];
    __shared__ short a_lds[BM * LDA];           // 33 KB
    __shared__ short b_lds[BN * LDA];           // 33 KB

    // ---- issue source loads (scan consumes first) ----
    int4 sv[8];
    const int4* sp = (const int4*)source + (size_t)t * 8;
    #pragma unroll
    for (int i = 0; i < 8; ++i) sv[i] = sp[i];

    // ---- issue W patch loads: 4 o x 16 k (coalesced 256B per k-row) ----
    const int k0 = (t >> 4) * 16;               // 0..240
    const int o0 = (t & 15) * 4;                // 0..60
    const float* wbase = kern + ((size_t)s * FDIM + k0) * ODIM + n0 + o0;
    float4 wv[16];
    #pragma unroll
    for (int i = 0; i < 16; ++i)
        wv[i] = *(const float4*)(wbase + (size_t)i * ODIM);

    // ---- scan: thread t owns rows [32t, 32t+32) ----
    int c = 0;
    #pragma unroll
    for (int i = 0; i < 8; ++i)
        c += (sv[i].x == s) + (sv[i].y == s) + (sv[i].z == s) + (sv[i].w == s);
    int p = c;
    #pragma unroll
    for (int d = 1; d < 64; d <<= 1) {
        const int v = __shfl_up(p, d);
        if (lane >= d) p += v;
    }
    if (lane == 63) wsum[wid] = p;
    __syncthreads();
    int r_base = p - c;                         // exclusive prefix in wave
    #pragma unroll
    for (int w = 0; w < 4; ++w) if (w < wid) r_base += wsum[w];
    const int cnt = wsum[0] + wsum[1] + wsum[2] + wsum[3];
    if (cnt <= lo0) return;                     // uniform: rare idle block

    // ---- first scatter (sv dies here) ----
    {
        int r = r_base;
        #pragma unroll
        for (int i = 0; i < 8; ++i) {
            const int base = t * 32 + i * 4;
            if (sv[i].x == s) { if (r >= lo0 && r < lo0 + BM) rows_lds[r - lo0] = base;     ++r; }
            if (sv[i].y == s) { if (r >= lo0 && r < lo0 + BM) rows_lds[r - lo0] = base + 1; ++r; }
            if (sv[i].z == s) { if (r >= lo0 && r < lo0 + BM) rows_lds[r - lo0] = base + 2; ++r; }
            if (sv[i].w == s) { if (r >= lo0 && r < lo0 + BM) rows_lds[r - lo0] = base + 3; ++r; }
        }
    }

    // ---- register-transpose W patch -> b_lds[o][k] (2 b128 per o-row) ----
    #pragma unroll
    for (int j = 0; j < 4; ++j) {
        uint4 q0, q1;
        q0.x = pk2(f4get(wv[0],  j), f4get(wv[1],  j));
        q0.y = pk2(f4get(wv[2],  j), f4get(wv[3],  j));
        q0.z = pk2(f4get(wv[4],  j), f4get(wv[5],  j));
        q0.w = pk2(f4get(wv[6],  j), f4get(wv[7],  j));
        q1.x = pk2(f4get(wv[8],  j), f4get(wv[9],  j));
        q1.y = pk2(f4get(wv[10], j), f4get(wv[11], j));
        q1.z = pk2(f4get(wv[12], j), f4get(wv[13], j));
        q1.w = pk2(f4get(wv[14], j), f4get(wv[15], j));
        char* dst = (char*)b_lds + (size_t)(o0 + j) * LDAB + 2 * k0;
        *(uint4*)(dst)      = q0;
        *(uint4*)(dst + 16) = q1;
    }

    const int lr = lane & 15;
    const int lg = lane >> 4;
    const int srow = 16 * wid + (lane >> 2);    // strip row this lane stages
    const int scol = (lane & 3) * 8;            // float col base (16B interleave)

    const float bv0 = bias[s * ODIM + n0 +      lr];
    const float bv1 = bias[s * ODIM + n0 + 16 + lr];
    const float bv2 = bias[s * ODIM + n0 + 32 + lr];
    const float bv3 = bias[s * ODIM + n0 + 48 + lr];

    int lo = lo0;
    __syncthreads();                            // rows_lds + b_lds published
    while (true) {
        const int nvalid = min(BM, cnt - lo);

        // ---- wave-local A stage: gather own strip rows ----
        const float* xrow = x + (size_t)rows_lds[(srow < nvalid) ? srow : 0] * FDIM + scol;
        float4 xv[16];
        #pragma unroll
        for (int j = 0; j < 8; ++j) {
            xv[2 * j]     = *(const float4*)(xrow + j * 32);
            xv[2 * j + 1] = *(const float4*)(xrow + j * 32 + 4);
        }
        {
            short* dst = &a_lds[srow * LDA + scol];
            #pragma unroll
            for (int j = 0; j < 8; ++j) {
                const float4 f0 = xv[2 * j];
                const float4 f1 = xv[2 * j + 1];
                uint4 pk;
                pk.x = pk2(f0.x, f0.y);
                pk.y = pk2(f0.z, f0.w);
                pk.z = pk2(f1.x, f1.y);
                pk.w = pk2(f1.z, f1.w);
                *(uint4*)(dst + j * 32) = pk;
            }
        }
        // wave-local fence: drain own DS writes; "memory" clobber blocks
        // compile-time reordering of the following LDS reads above it.
        asm volatile("s_waitcnt lgkmcnt(0)" ::: "memory");

        // ---- MFMA: 1x4 frags, A rows = own strip (wave-local) ----
        f32x4 acc0 = {}, acc1 = {}, acc2 = {}, acc3 = {};
        const short* ab = &a_lds[(16 * wid + lr) * LDA + 8 * lg];
        const short* bb = &b_lds[lr * LDA + 8 * lg];
        #pragma unroll
        for (int kk = 0; kk < 8; ++kk) {
            const s16x8 a  = *(const s16x8*)(ab + kk * 32);
            const s16x8 b0 = *(const s16x8*)(bb + kk * 32);
            const s16x8 b1 = *(const s16x8*)(bb + kk * 32 + 16 * LDA);
            const s16x8 b2 = *(const s16x8*)(bb + kk * 32 + 32 * LDA);
            const s16x8 b3 = *(const s16x8*)(bb + kk * 32 + 48 * LDA);
            acc0 = __builtin_amdgcn_mfma_f32_16x16x32_bf16(a, b0, acc0, 0, 0, 0);
            acc1 = __builtin_amdgcn_mfma_f32_16x16x32_bf16(a, b1, acc1, 0, 0, 0);
            acc2 = __builtin_amdgcn_mfma_f32_16x16x32_bf16(a, b2, acc2, 0, 0, 0);
            acc3 = __builtin_amdgcn_mfma_f32_16x16x32_bf16(a, b3, acc3, 0, 0, 0);
        }

        // ---- epilogue: D[row=16w+4lg+rr][col=16b+lr]; bias + scatter ----
        #pragma unroll
        for (int rr = 0; rr < 4; ++rr) {
            const int lm = 16 * wid + 4 * lg + rr;
            if (lm < nvalid) {
                float* orow = out + (size_t)rows_lds[lm] * ODIM + n0;
                orow[lr]      = acc0[rr] + bv0;
                orow[lr + 16] = acc1[rr] + bv1;
                orow[lr + 32] = acc2[rr] + bv2;
                orow[lr + 48] = acc3[rr] + bv3;
            }
        }

        // overflow: only the last chunk loops (cnt > 512 is a rare tail)
        lo += BM;
        if (!(mc == MCHUNKS - 1 && lo < cnt)) break;
        __syncthreads();                        // all waves done with rows_lds
        {
            int r = r_base;
            #pragma unroll
            for (int i = 0; i < 8; ++i) {
                const int4 s2 = sp[i];          // reload (rare path)
                const int base = t * 32 + i * 4;
                if (s2.x == s) { if (r >= lo && r < lo + BM) rows_lds[r - lo] = base;     ++r; }
                if (s2.y == s) { if (r >= lo && r < lo + BM) rows_lds[r - lo] = base + 1; ++r; }
                if (s2.z == s) { if (r >= lo && r < lo + BM) rows_lds[r - lo] = base + 2; ++r; }
                if (s2.w == s) { if (r >= lo && r < lo + BM) rows_lds[r - lo] = base + 3; ++r; }
            }
        }
        __syncthreads();                        // new rows_lds published
    }
}

// ---------------------------------------------------------------------------
extern "C" void kernel_launch(void* const* d_in, const int* in_sizes, int n_in,
                              void* d_out, int out_size, void* d_ws, size_t ws_size,
                              hipStream_t stream) {
    const float* x      = (const float*)d_in[0];
    const int*   source = (const int*)d_in[1];
    const float* kern   = (const float*)d_in[2];
    const float* bias   = (const float*)d_in[3];
    float*       out    = (float*)d_out;

    hipLaunchKernelGGL(fused_k, dim3(NWG), dim3(256), 0, stream,
                       x, source, kern, bias, out);
}